// Round 6
// baseline (91.637 us; speedup 1.0000x reference)
//
#include <hip/hip_runtime.h>
#include <stdint.h>

// Sizes fixed by the problem.
#define DM 1024   // D_MODEL
#define NN 2048   // NUM_NEURONS
#define BB 64     // batch (== wavefront size!)

static constexpr float INV2PI = 0.15915494309189535f;

__device__ __forceinline__ uint32_t bf16r(float x) {
  uint32_t b = __float_as_uint(x);
  b += 0x7fffu + ((b >> 16) & 1u);
  return b >> 16;
}

// ---------------- K0: prep ----------------
// blocks [0,32):   xcombP tiles (x_real/x_imag [64][1024] -> [1024 kpair][64 b] float2)
// blocks [32,288): rinv = 1/(1+|W|) elementwise (2M f32)
__global__ __launch_bounds__(256) void k0_prep(
    const float* __restrict__ xr, const float* __restrict__ xi,
    const float* __restrict__ W,
    float* __restrict__ xcombP, float* __restrict__ rinv)
{
  __shared__ float tile[64][65];
  int bid = blockIdx.x;
  int t = threadIdx.x;
  if (bid < 32) {
    int j = bid;  // k-tile of 64 over concatenated 2048
    int k0 = j * 64;
    const float* src = (k0 < 1024) ? xr : xi;
    int koff = k0 & 1023;
    int c = t & 63, rl = t >> 6;
#pragma unroll
    for (int i = 0; i < 16; ++i) {
      int b = rl * 16 + i;
      tile[b][c] = src[b * 1024 + koff + c];  // tile[b][k_local]
    }
    __syncthreads();
    float2* out2 = (float2*)xcombP;  // [1024 kpair][64 b]
    int bl = t & 63, kp = t >> 6;    // kp 0..3
#pragma unroll
    for (int i = 0; i < 8; ++i) {
      int kl = (kp * 8 + i) * 2;
      float2 v = make_float2(tile[bl][kl], tile[bl][kl + 1]);
      out2[(size_t)((k0 + kl) >> 1) * 64 + bl] = v;
    }
  } else {
    int j = bid - 32;  // 0..255, 2048 float4 each over 524288 total
    const float4* W4 = (const float4*)W;
    float4* R4 = (float4*)rinv;
    int base = j * 2048 + t;
#pragma unroll
    for (int i = 0; i < 8; ++i) {
      int idx = base + i * 256;
      float4 w = W4[idx];
      float4 r;
      r.x = 1.0f / (1.0f + fabsf(w.x));
      r.y = 1.0f / (1.0f + fabsf(w.y));
      r.z = 1.0f / (1.0f + fabsf(w.z));
      r.w = 1.0f / (1.0f + fabsf(w.w));
      R4[idx] = r;
    }
  }
}

// ---------------- K1: x_collapsed ----------------
// xc[b,d] = sum_k xcomb[b,k]*ic_w[d,k] + ic_b[d]; packed bf16 pairs of
// xc*INV2PI -> xcp[d/2][b]. d-tile 2 (512 blocks), 1-iter src prefetch.
__global__ __launch_bounds__(512) void k1_collapse(
    const float* __restrict__ xcombP, const float* __restrict__ icw,
    const float* __restrict__ icb, uint32_t* __restrict__ xcp)
{
  __shared__ float part[8][2][64];
  int d0 = blockIdx.x * 2;
  int wave = __builtin_amdgcn_readfirstlane((int)(threadIdx.x >> 6));
  int lane = threadIdx.x & 63;
  const float2* P2 = (const float2*)xcombP;
  float acc0 = 0.f, acc1 = 0.f;
  int kbase = wave * 256;
  float2 xa = P2[(size_t)(kbase >> 1) * 64 + lane];
  float2 xb = P2[(size_t)((kbase >> 1) + 1) * 64 + lane];
  for (int kk = 0; kk < 256; kk += 4) {
    int k = kbase + kk;
    int kn = (kk < 252) ? (k + 4) : kbase;  // prefetch next (wrap: dead value)
    float2 na = P2[(size_t)(kn >> 1) * 64 + lane];
    float2 nb = P2[(size_t)((kn >> 1) + 1) * 64 + lane];
    float4 w0 = *(const float4*)(icw + (size_t)d0 * 2048 + k);        // s_load
    float4 w1 = *(const float4*)(icw + (size_t)(d0 + 1) * 2048 + k);  // s_load
    acc0 = fmaf(w0.x, xa.x, acc0);
    acc0 = fmaf(w0.y, xa.y, acc0);
    acc0 = fmaf(w0.z, xb.x, acc0);
    acc0 = fmaf(w0.w, xb.y, acc0);
    acc1 = fmaf(w1.x, xa.x, acc1);
    acc1 = fmaf(w1.y, xa.y, acc1);
    acc1 = fmaf(w1.z, xb.x, acc1);
    acc1 = fmaf(w1.w, xb.y, acc1);
    xa = na; xb = nb;
  }
  part[wave][0][lane] = acc0;
  part[wave][1][lane] = acc1;
  __syncthreads();
  int t = threadIdx.x;
  if (t < 64) {
    int b = t;
    float s0 = 0.f, s1 = 0.f;
#pragma unroll
    for (int w = 0; w < 8; ++w) {
      s0 += part[w][0][b];
      s1 += part[w][1][b];
    }
    float x0 = (s0 + icb[d0]) * INV2PI;
    float x1 = (s1 + icb[d0 + 1]) * INV2PI;
    uint32_t u = bf16r(x0) | (bf16r(x1) << 16);
    xcp[(size_t)(d0 >> 1) * 64 + b] = u;
  }
}

// ---------------- K2: the resonant map-reduce (dominant) ----------------
// lane = b. wave owns (n, d-quarter q). Block stages the shared 32 KB xcp
// q-slice into LDS once (cooperative, 1 barrier); params double-buffered
// per-wave via global_load_lds. Inner loop: pure LDS + VALU (trans-bound).
#define K2_STEP(r4, b4, a4, s4, xu0, xu1)                                 \
  do {                                                                     \
    float x0 = __uint_as_float((xu0) << 16);                               \
    float x1 = __uint_as_float((xu0) & 0xffff0000u);                       \
    float x2 = __uint_as_float((xu1) << 16);                               \
    float x3 = __uint_as_float((xu1) & 0xffff0000u);                       \
    float rv0 = fmaf(x0, (r4).x, fmaf((b4).x, INV2PI, t2));                \
    accc0 = fmaf(__builtin_amdgcn_cosf(rv0), (a4).x, accc0);               \
    accs0 = fmaf(__builtin_amdgcn_sinf(rv0), (s4).x, accs0);               \
    float rv1 = fmaf(x1, (r4).y, fmaf((b4).y, INV2PI, t2));                \
    accc1 = fmaf(__builtin_amdgcn_cosf(rv1), (a4).y, accc1);               \
    accs1 = fmaf(__builtin_amdgcn_sinf(rv1), (s4).y, accs1);               \
    float rv2 = fmaf(x2, (r4).z, fmaf((b4).z, INV2PI, t2));                \
    accc0 = fmaf(__builtin_amdgcn_cosf(rv2), (a4).z, accc0);               \
    accs0 = fmaf(__builtin_amdgcn_sinf(rv2), (s4).z, accs0);               \
    float rv3 = fmaf(x3, (r4).w, fmaf((b4).w, INV2PI, t2));                \
    accc1 = fmaf(__builtin_amdgcn_cosf(rv3), (a4).w, accc1);               \
    accs1 = fmaf(__builtin_amdgcn_sinf(rv3), (s4).w, accs1);               \
  } while (0)

__global__ __launch_bounds__(512) void k2_resonant(
    const uint32_t* __restrict__ xcp, const float* __restrict__ rinv,
    const float* __restrict__ Bp, const float* __restrict__ ac,
    const float* __restrict__ as_, const float* __restrict__ tin,
    float* __restrict__ csP, float* __restrict__ ssP)
{
  __shared__ __align__(16) uint32_t xlds[128][64];   // 32 KB: q-slice of xcp
  __shared__ __align__(16) float plds[2][8][4][64];  // 16 KB: param dbuf
  int wave = __builtin_amdgcn_readfirstlane((int)(threadIdx.x >> 6));
  int lane = threadIdx.x & 63;
  int bid = blockIdx.x;
  int q = bid & 3;                 // d-quarter
  int n = (bid >> 2) * 8 + wave;   // neuron
  float t2 = tin[lane] * INV2PI;

  // ---- stage xcp q-slice: 32 calls x 1 KB; wave w does calls w*4..w*4+3
  const char* xsrc = (const char*)(xcp + (size_t)q * 128 * 64);
  char* xdst = (char*)&xlds[0][0];
#pragma unroll
  for (int r = 0; r < 4; ++r) {
    int j = wave * 4 + r;
    __builtin_amdgcn_global_load_lds(
        (const __attribute__((address_space(1))) void*)(xsrc + j * 1024 + lane * 16),
        (__attribute__((address_space(3))) void*)(xdst + j * 1024), 16, 0, 0);
  }

  // ---- param stage source: lane l -> array (l>>4), elements (l&15)*4
  int g = lane >> 4;
  const float* ab = (g == 0) ? rinv : (g == 1) ? Bp : (g == 2) ? ac : as_;
  const float* gp = ab + (size_t)n * 1024 + (size_t)q * 256 + (lane & 15) * 4;
  __builtin_amdgcn_global_load_lds(
      (const __attribute__((address_space(1))) void*)gp,
      (__attribute__((address_space(3))) void*)&plds[0][wave][0][0], 16, 0, 0);

  __syncthreads();  // xcp slice visible to all waves (drains vmcnt)

  float accc0 = 0.f, accs0 = 0.f, accc1 = 0.f, accs1 = 0.f;

#pragma unroll
  for (int c = 0; c < 4; ++c) {
    if (c < 3) {
      __builtin_amdgcn_global_load_lds(
          (const __attribute__((address_space(1))) void*)(gp + (c + 1) * 64),
          (__attribute__((address_space(3))) void*)&plds[(c + 1) & 1][wave][0][0],
          16, 0, 0);
      asm volatile("s_waitcnt vmcnt(1)" ::: "memory");  // chunk c ready
    } else {
      asm volatile("s_waitcnt vmcnt(0)" ::: "memory");
    }
    const float4* pr = (const float4*)&plds[c & 1][wave][0][0];  // [4][16]
#pragma unroll 4
    for (int i = 0; i < 16; ++i) {
      int ga = c * 16 + i;
      uint32_t xu0 = xlds[2 * ga][lane];
      uint32_t xu1 = xlds[2 * ga + 1][lane];
      float4 r4 = pr[i];
      float4 b4 = pr[16 + i];
      float4 a4 = pr[32 + i];
      float4 s4 = pr[48 + i];
      K2_STEP(r4, b4, a4, s4, xu0, xu1);
    }
  }

  size_t o = ((size_t)q * 2048 + n) * 64 + lane;
  csP[o] = accc0 + accc1;
  ssP[o] = accs0 + accs1;
}

// ---------------- K2b: sum the 4 d-quarter partials ----------------
__global__ __launch_bounds__(256) void k2b_reduce(
    const float* __restrict__ csP, const float* __restrict__ ssP,
    float* __restrict__ csT, float* __restrict__ ssT)
{
  int i = blockIdx.x * 256 + threadIdx.x;  // 0..131071
  float c = csP[i] + csP[i + 131072] + csP[i + 262144] + csP[i + 393216];
  float s = ssP[i] + ssP[i + 131072] + ssP[i + 262144] + ssP[i + 393216];
  csT[i] = c;
  ssT[i] = s;
}

// ---------------- K3: output GEMMs + SiLU ----------------
// out[sel][b][d] = silu(sum_n src[n][b] * w[d][n]); d-tile 2 (1024 blocks),
// w rows via s_load (n wave-uniform), 1-iter prefetch of src columns.
__global__ __launch_bounds__(512) void k3_out(
    const float* __restrict__ csT, const float* __restrict__ ssT,
    const float* __restrict__ wr, const float* __restrict__ wi,
    float* __restrict__ out)
{
  __shared__ float part[8][2][64];
  int bid = blockIdx.x;
  int sel = bid >> 9;
  int d0 = (bid & 511) * 2;
  int wave = __builtin_amdgcn_readfirstlane((int)(threadIdx.x >> 6));
  int lane = threadIdx.x & 63;
  const float* src = sel ? ssT : csT;
  const float* wt = sel ? wi : wr;
  float acc0 = 0.f, acc1 = 0.f;
  int n0 = wave * 256;
  float cv0 = src[(size_t)(n0 + 0) * 64 + lane];
  float cv1 = src[(size_t)(n0 + 1) * 64 + lane];
  float cv2 = src[(size_t)(n0 + 2) * 64 + lane];
  float cv3 = src[(size_t)(n0 + 3) * 64 + lane];
  for (int i = 0; i < 64; ++i) {
    int n = n0 + i * 4;
    int nn = (i < 63) ? (n + 4) : n0;  // prefetch next (wrap: dead value)
    float nv0 = src[(size_t)(nn + 0) * 64 + lane];
    float nv1 = src[(size_t)(nn + 1) * 64 + lane];
    float nv2 = src[(size_t)(nn + 2) * 64 + lane];
    float nv3 = src[(size_t)(nn + 3) * 64 + lane];
    float4 w0 = *(const float4*)(wt + (size_t)d0 * 2048 + n);        // s_load
    float4 w1 = *(const float4*)(wt + (size_t)(d0 + 1) * 2048 + n);  // s_load
    acc0 = fmaf(cv0, w0.x, acc0);
    acc0 = fmaf(cv1, w0.y, acc0);
    acc0 = fmaf(cv2, w0.z, acc0);
    acc0 = fmaf(cv3, w0.w, acc0);
    acc1 = fmaf(cv0, w1.x, acc1);
    acc1 = fmaf(cv1, w1.y, acc1);
    acc1 = fmaf(cv2, w1.z, acc1);
    acc1 = fmaf(cv3, w1.w, acc1);
    cv0 = nv0; cv1 = nv1; cv2 = nv2; cv3 = nv3;
  }
  part[wave][0][lane] = acc0;
  part[wave][1][lane] = acc1;
  __syncthreads();
  int t = threadIdx.x;
  if (t < 128) {
    int b = t >> 1, j = t & 1;
    float s = 0.f;
#pragma unroll
    for (int w = 0; w < 8; ++w) s += part[w][j][b];
    float y = s / (1.0f + __expf(-s));  // silu
    out[(size_t)sel * 65536 + (size_t)b * 1024 + d0 + j] = y;
  }
}

extern "C" void kernel_launch(void* const* d_in, const int* in_sizes, int n_in,
                              void* d_out, int out_size, void* d_ws, size_t ws_size,
                              hipStream_t stream) {
  const float* xr  = (const float*)d_in[0];
  const float* xi  = (const float*)d_in[1];
  const float* t   = (const float*)d_in[2];
  const float* icw = (const float*)d_in[3];
  const float* icb = (const float*)d_in[4];
  const float* W   = (const float*)d_in[5];
  const float* Bp  = (const float*)d_in[6];
  const float* ac  = (const float*)d_in[7];
  const float* as_ = (const float*)d_in[8];
  const float* wr  = (const float*)d_in[9];
  const float* wi  = (const float*)d_in[10];
  // sin/cos tables (d_in[11], d_in[12]) replaced by hw v_sin/v_cos (err ~1e-6)

  float* ws = (float*)d_ws;
  float* rinv   = ws;                          // 2M f32
  float* xcombP = ws + 2097152;                // 131072
  uint32_t* xcp = (uint32_t*)(ws + 2228224);   // 32768 u32
  float* csP    = ws + 2260992;                // 524288 (4 x 2048 x 64)
  float* ssP    = ws + 2785280;                // 524288
  float* csT    = ws + 3309568;                // 131072
  float* ssT    = ws + 3440640;                // 131072
  float* out = (float*)d_out;

  k0_prep<<<dim3(288), dim3(256), 0, stream>>>(xr, xi, W, xcombP, rinv);
  k1_collapse<<<dim3(512), dim3(512), 0, stream>>>(xcombP, icw, icb, xcp);
  k2_resonant<<<dim3(1024), dim3(512), 0, stream>>>(xcp, rinv, Bp, ac, as_, t, csP, ssP);
  k2b_reduce<<<dim3(512), dim3(256), 0, stream>>>(csP, ssP, csT, ssT);
  k3_out<<<dim3(1024), dim3(512), 0, stream>>>(csT, ssT, wr, wi, out);
}

// Round 7
// 78.200 us; speedup vs baseline: 1.1718x; 1.1718x over previous
//
#include <hip/hip_runtime.h>
#include <stdint.h>

// Sizes fixed by the problem.
#define DM 1024   // D_MODEL
#define NN 2048   // NUM_NEURONS
#define BB 64     // batch (== wavefront size!)

static constexpr float INV2PI = 0.15915494309189535f;

__device__ __forceinline__ uint32_t bf16r(float x) {
  uint32_t b = __float_as_uint(x);
  b += 0x7fffu + ((b >> 16) & 1u);
  return b >> 16;
}

// ---------------- K0: prep ----------------
// blocks [0,32):   xcombP tiles (x_real/x_imag [64][1024] -> [1024 kpair][64 b] float2)
// blocks [32,288): rinv = 1/(1+|W|) elementwise (2M f32)
__global__ __launch_bounds__(256) void k0_prep(
    const float* __restrict__ xr, const float* __restrict__ xi,
    const float* __restrict__ W,
    float* __restrict__ xcombP, float* __restrict__ rinv)
{
  __shared__ float tile[64][65];
  int bid = blockIdx.x;
  int t = threadIdx.x;
  if (bid < 32) {
    int j = bid;  // k-tile of 64 over concatenated 2048
    int k0 = j * 64;
    const float* src = (k0 < 1024) ? xr : xi;
    int koff = k0 & 1023;
    int c = t & 63, rl = t >> 6;
#pragma unroll
    for (int i = 0; i < 16; ++i) {
      int b = rl * 16 + i;
      tile[b][c] = src[b * 1024 + koff + c];  // tile[b][k_local]
    }
    __syncthreads();
    float2* out2 = (float2*)xcombP;  // [1024 kpair][64 b]
    int bl = t & 63, kp = t >> 6;    // kp 0..3
#pragma unroll
    for (int i = 0; i < 8; ++i) {
      int kl = (kp * 8 + i) * 2;
      float2 v = make_float2(tile[bl][kl], tile[bl][kl + 1]);
      out2[(size_t)((k0 + kl) >> 1) * 64 + bl] = v;
    }
  } else {
    int j = bid - 32;  // 0..255, 2048 float4 each over 524288 total
    const float4* W4 = (const float4*)W;
    float4* R4 = (float4*)rinv;
    int base = j * 2048 + t;
#pragma unroll
    for (int i = 0; i < 8; ++i) {
      int idx = base + i * 256;
      float4 w = W4[idx];
      float4 r;
      r.x = 1.0f / (1.0f + fabsf(w.x));
      r.y = 1.0f / (1.0f + fabsf(w.y));
      r.z = 1.0f / (1.0f + fabsf(w.z));
      r.w = 1.0f / (1.0f + fabsf(w.w));
      R4[idx] = r;
    }
  }
}

// ---------------- K1: x_collapsed (R4-proven form, d-tile 4) ----------------
// xc[b,d] = sum_k xcomb[b,k]*ic_w[d,k] + ic_b[d]; store packed bf16 pairs of
// xc*INV2PI as xcp[d/2][b].
__global__ __launch_bounds__(512) void k1_collapse(
    const float* __restrict__ xcombP, const float* __restrict__ icw,
    const float* __restrict__ icb, uint32_t* __restrict__ xcp)
{
  __shared__ float part[8][4][64];
  int d0 = blockIdx.x * 4;
  int wave = __builtin_amdgcn_readfirstlane((int)(threadIdx.x >> 6));
  int lane = threadIdx.x & 63;
  const float2* P2 = (const float2*)xcombP;
  float acc[4] = {0.f, 0.f, 0.f, 0.f};
  int kbase = wave * 256;
  for (int kk = 0; kk < 256; kk += 4) {
    int k = kbase + kk;
    float2 xa = P2[(size_t)(k >> 1) * 64 + lane];        // k, k+1
    float2 xb = P2[(size_t)((k >> 1) + 1) * 64 + lane];  // k+2, k+3
#pragma unroll
    for (int r = 0; r < 4; ++r) {
      float4 w = *(const float4*)(icw + (size_t)(d0 + r) * 2048 + k);  // s_load
      acc[r] = fmaf(w.x, xa.x, acc[r]);
      acc[r] = fmaf(w.y, xa.y, acc[r]);
      acc[r] = fmaf(w.z, xb.x, acc[r]);
      acc[r] = fmaf(w.w, xb.y, acc[r]);
    }
  }
#pragma unroll
  for (int r = 0; r < 4; ++r) part[wave][r][lane] = acc[r];
  __syncthreads();
  int t = threadIdx.x;
  if (t < 128) {
    int pj = t >> 6;  // 0..1 (d-pair within tile)
    int b = t & 63;
    float s0 = 0.f, s1 = 0.f;
#pragma unroll
    for (int w = 0; w < 8; ++w) {
      s0 += part[w][2 * pj][b];
      s1 += part[w][2 * pj + 1][b];
    }
    float x0 = (s0 + icb[d0 + 2 * pj]) * INV2PI;
    float x1 = (s1 + icb[d0 + 2 * pj + 1]) * INV2PI;
    uint32_t u = bf16r(x0) | (bf16r(x1) << 16);
    xcp[(size_t)((d0 >> 1) + pj) * 64 + b] = u;
  }
}

// ---------------- K2: the resonant map-reduce (dominant) ----------------
// lane = b. wave owns (n, d-eighth q). 2048 blocks x 8 waves. LDS = 32 KB ->
// 4 blocks/CU = 32 waves (full occupancy). ALL staging (xcp eighth-slice
// cooperative + both param chunks per wave) issued before ONE barrier; the
// inner loop is pure LDS+VALU+trans, zero waits, zero global loads.
#define K2_STEP(r4, b4, a4, s4, xu0, xu1)                                 \
  do {                                                                     \
    float x0 = __uint_as_float((xu0) << 16);                               \
    float x1 = __uint_as_float((xu0) & 0xffff0000u);                       \
    float x2 = __uint_as_float((xu1) << 16);                               \
    float x3 = __uint_as_float((xu1) & 0xffff0000u);                       \
    float rv0 = fmaf(x0, (r4).x, fmaf((b4).x, INV2PI, t2));                \
    accc0 = fmaf(__builtin_amdgcn_cosf(rv0), (a4).x, accc0);               \
    accs0 = fmaf(__builtin_amdgcn_sinf(rv0), (s4).x, accs0);               \
    float rv1 = fmaf(x1, (r4).y, fmaf((b4).y, INV2PI, t2));                \
    accc1 = fmaf(__builtin_amdgcn_cosf(rv1), (a4).y, accc1);               \
    accs1 = fmaf(__builtin_amdgcn_sinf(rv1), (s4).y, accs1);               \
    float rv2 = fmaf(x2, (r4).z, fmaf((b4).z, INV2PI, t2));                \
    accc0 = fmaf(__builtin_amdgcn_cosf(rv2), (a4).z, accc0);               \
    accs0 = fmaf(__builtin_amdgcn_sinf(rv2), (s4).z, accs0);               \
    float rv3 = fmaf(x3, (r4).w, fmaf((b4).w, INV2PI, t2));                \
    accc1 = fmaf(__builtin_amdgcn_cosf(rv3), (a4).w, accc1);               \
    accs1 = fmaf(__builtin_amdgcn_sinf(rv3), (s4).w, accs1);               \
  } while (0)

__global__ __launch_bounds__(512) void k2_resonant(
    const uint32_t* __restrict__ xcp, const float* __restrict__ rinv,
    const float* __restrict__ Bp, const float* __restrict__ ac,
    const float* __restrict__ as_, const float* __restrict__ tin,
    float* __restrict__ csP, float* __restrict__ ssP)
{
  __shared__ __align__(16) uint32_t xlds[64][64];    // 16 KB: d-eighth of xcp
  __shared__ __align__(16) float plds[2][8][4][64];  // 16 KB: params, 2 chunks
  int wave = __builtin_amdgcn_readfirstlane((int)(threadIdx.x >> 6));
  int lane = threadIdx.x & 63;
  int bid = blockIdx.x;
  int q = bid & 7;                 // d-eighth
  int n = (bid >> 3) * 8 + wave;   // neuron
  float t2 = tin[lane] * INV2PI;

  // ---- stage xcp eighth-slice (64 rows): 16 x 1KB calls; wave w does 2
  const char* xsrc = (const char*)(xcp + (size_t)q * 64 * 64);
  char* xdst = (char*)&xlds[0][0];
#pragma unroll
  for (int r = 0; r < 2; ++r) {
    int j = wave * 2 + r;  // call j stages rows 4j..4j+3
    __builtin_amdgcn_global_load_lds(
        (const __attribute__((address_space(1))) void*)(xsrc + j * 1024 + lane * 16),
        (__attribute__((address_space(3))) void*)(xdst + j * 1024), 16, 0, 0);
  }

  // ---- stage BOTH param chunks for this wave (no double-buffer dance)
  // lane l -> array (l>>4), elements (l&15)*4
  int g = lane >> 4;
  const float* ab = (g == 0) ? rinv : (g == 1) ? Bp : (g == 2) ? ac : as_;
  const float* gp = ab + (size_t)n * 1024 + (size_t)q * 128 + (lane & 15) * 4;
#pragma unroll
  for (int c = 0; c < 2; ++c) {
    __builtin_amdgcn_global_load_lds(
        (const __attribute__((address_space(1))) void*)(gp + c * 64),
        (__attribute__((address_space(3))) void*)&plds[c][wave][0][0], 16, 0, 0);
  }

  __syncthreads();  // drains vmcnt: all LDS staging complete

  float accc0 = 0.f, accs0 = 0.f, accc1 = 0.f, accs1 = 0.f;

#pragma unroll
  for (int c = 0; c < 2; ++c) {
    const float4* pr = (const float4*)&plds[c][wave][0][0];  // [4][16]
#pragma unroll 4
    for (int i = 0; i < 16; ++i) {
      int ga = c * 16 + i;
      uint32_t xu0 = xlds[2 * ga][lane];
      uint32_t xu1 = xlds[2 * ga + 1][lane];
      float4 r4 = pr[i];
      float4 b4 = pr[16 + i];
      float4 a4 = pr[32 + i];
      float4 s4 = pr[48 + i];
      K2_STEP(r4, b4, a4, s4, xu0, xu1);
    }
  }

  size_t o = ((size_t)q * 2048 + n) * 64 + lane;
  csP[o] = accc0 + accc1;
  ssP[o] = accs0 + accs1;
}

// ---------------- K2b: sum the 8 d-eighth partials ----------------
__global__ __launch_bounds__(256) void k2b_reduce(
    const float* __restrict__ csP, const float* __restrict__ ssP,
    float* __restrict__ csT, float* __restrict__ ssT)
{
  int i = blockIdx.x * 256 + threadIdx.x;  // 0..131071
  float c = 0.f, s = 0.f;
#pragma unroll
  for (int j = 0; j < 8; ++j) {
    c += csP[i + j * 131072];
    s += ssP[i + j * 131072];
  }
  csT[i] = c;
  ssT[i] = s;
}

// ---------------- K3: output GEMMs + SiLU (R4-proven form, d-tile 4) -------
// out[sel][b][d] = silu(sum_n src[n][b] * w[d][n]); w rows via s_load.
__global__ __launch_bounds__(512) void k3_out(
    const float* __restrict__ csT, const float* __restrict__ ssT,
    const float* __restrict__ wr, const float* __restrict__ wi,
    float* __restrict__ out)
{
  __shared__ float part[8][4][65];
  int bid = blockIdx.x;
  int sel = bid >> 8;
  int d0 = (bid & 255) * 4;
  int wave = __builtin_amdgcn_readfirstlane((int)(threadIdx.x >> 6));
  int lane = threadIdx.x & 63;
  const float* src = sel ? ssT : csT;
  const float* wt = sel ? wi : wr;
  float acc[4] = {0.f, 0.f, 0.f, 0.f};
  int n0 = wave * 256;
  for (int i = 0; i < 64; ++i) {
    int n = n0 + i * 4;
    float cv0 = src[(size_t)(n + 0) * 64 + lane];
    float cv1 = src[(size_t)(n + 1) * 64 + lane];
    float cv2 = src[(size_t)(n + 2) * 64 + lane];
    float cv3 = src[(size_t)(n + 3) * 64 + lane];
#pragma unroll
    for (int r = 0; r < 4; ++r) {
      float4 wv = *(const float4*)(wt + (size_t)(d0 + r) * 2048 + n);  // s_load
      acc[r] = fmaf(cv0, wv.x, acc[r]);
      acc[r] = fmaf(cv1, wv.y, acc[r]);
      acc[r] = fmaf(cv2, wv.z, acc[r]);
      acc[r] = fmaf(cv3, wv.w, acc[r]);
    }
  }
#pragma unroll
  for (int r = 0; r < 4; ++r) part[wave][r][lane] = acc[r];
  __syncthreads();
  int t = threadIdx.x;
  if (t < 256) {
    int b = t >> 2, j = t & 3;
    float s = 0.f;
#pragma unroll
    for (int w = 0; w < 8; ++w) s += part[w][j][b];
    float y = s / (1.0f + __expf(-s));  // silu
    out[(size_t)sel * 65536 + (size_t)b * 1024 + d0 + j] = y;
  }
}

extern "C" void kernel_launch(void* const* d_in, const int* in_sizes, int n_in,
                              void* d_out, int out_size, void* d_ws, size_t ws_size,
                              hipStream_t stream) {
  const float* xr  = (const float*)d_in[0];
  const float* xi  = (const float*)d_in[1];
  const float* t   = (const float*)d_in[2];
  const float* icw = (const float*)d_in[3];
  const float* icb = (const float*)d_in[4];
  const float* W   = (const float*)d_in[5];
  const float* Bp  = (const float*)d_in[6];
  const float* ac  = (const float*)d_in[7];
  const float* as_ = (const float*)d_in[8];
  const float* wr  = (const float*)d_in[9];
  const float* wi  = (const float*)d_in[10];
  // sin/cos tables (d_in[11], d_in[12]) replaced by hw v_sin/v_cos (err ~1e-6)

  float* ws = (float*)d_ws;
  float* rinv   = ws;                          // 2M f32
  float* xcombP = ws + 2097152;                // 131072
  uint32_t* xcp = (uint32_t*)(ws + 2228224);   // 32768 u32
  float* csP    = ws + 2260992;                // 1048576 (8 x 2048 x 64)
  float* ssP    = ws + 3309568;                // 1048576
  float* csT    = ws + 4358144;                // 131072
  float* ssT    = ws + 4489216;                // 131072
  float* out = (float*)d_out;

  k0_prep<<<dim3(288), dim3(256), 0, stream>>>(xr, xi, W, xcombP, rinv);
  k1_collapse<<<dim3(256), dim3(512), 0, stream>>>(xcombP, icw, icb, xcp);
  k2_resonant<<<dim3(2048), dim3(512), 0, stream>>>(xcp, rinv, Bp, ac, as_, t, csP, ssP);
  k2b_reduce<<<dim3(512), dim3(256), 0, stream>>>(csP, ssP, csT, ssT);
  k3_out<<<dim3(512), dim3(512), 0, stream>>>(csT, ssT, wr, wi, out);
}